// Round 4
// baseline (758.107 us; speedup 1.0000x reference)
//
#include <hip/hip_runtime.h>
#include <stdint.h>

#define B_TOTAL 4096
#define T_STEPS 512
#define IN_DIM 16
#define H1 5
#define H2 50
#define NCLS 20

typedef __attribute__((ext_vector_type(8))) short bf16x8;
typedef __attribute__((ext_vector_type(4))) float f32x4;

#define LOG2E 1.44269504f
__device__ inline float sigm(float x){
  float e = __builtin_amdgcn_exp2f(-LOG2E * x);
  return __builtin_amdgcn_rcpf(1.0f + e);
}
__device__ inline float tanh_(float x){
  float e = __builtin_amdgcn_exp2f((2.0f*LOG2E) * x);
  float r = __builtin_amdgcn_rcpf(1.0f + e);
  return fmaf(-2.0f, r, 1.0f);
}
// dword = [top16(a) | top16(b)]  (memory shorts: [0]=b, [1]=a)
__device__ inline unsigned pack_top(float a, float b){
  return __builtin_amdgcn_perm(__float_as_uint(a), __float_as_uint(b), 0x07060302u);
}
__device__ inline void cvt_store(unsigned short* dh, unsigned short* dl, float4 v){
  uint2 H, L;
  H.x = pack_top(v.y, v.x);
  H.y = pack_top(v.w, v.z);
  float r0 = v.x - __uint_as_float(__float_as_uint(v.x) & 0xFFFF0000u);
  float r1 = v.y - __uint_as_float(__float_as_uint(v.y) & 0xFFFF0000u);
  float r2 = v.z - __uint_as_float(__float_as_uint(v.z) & 0xFFFF0000u);
  float r3 = v.w - __uint_as_float(__float_as_uint(v.w) & 0xFFFF0000u);
  L.x = pack_top(r1, r0);
  L.y = pack_top(r3, r2);
  *(uint2*)dh = H; *(uint2*)dl = L;
}
__device__ inline void split1(float h, unsigned short& hi, unsigned short& lo){
  unsigned u = __float_as_uint(h);
  hi = (unsigned short)(u >> 16);
  float r = h - __uint_as_float(u & 0xFFFF0000u);
  lo = (unsigned short)(__float_as_uint(r) >> 16);
}
__device__ inline void wsplit(float w, short& hi, short& lo){
  unsigned u = __float_as_uint(w);
  hi = (short)(u >> 16);
  float r = w - __uint_as_float(u & 0xFFFF0000u);
  lo = (short)(__float_as_uint(r) >> 16);
}
__device__ inline void spin_ge(unsigned* p, unsigned tgt){
  while (__hip_atomic_load(p, __ATOMIC_ACQUIRE, __HIP_MEMORY_SCOPE_WORKGROUP) < tgt)
    __builtin_amdgcn_s_sleep(1);
}

// Fused 2-layer LSTM + FC. grid 256 (16-batch tiles), block 320 (5 waves).
// NO block barrier in the t-loop. Waves 0-3: lstm2, each owns 16 cell-cols and
// all 4 gate types (gates stay in registers). Sync among them: LDS counter cnt2
// (+1 per wave per step). Wave 4: lstm1 fully in-wave (private a1/x-ring LDS),
// runs ahead, publishes h1(t) into a2[t&1] and bumps cnt1; throttled by cnt2.
// a2 is double-buffered: step t reads a2[t&1] (h2(t-1), h1(t)), writes a2[~t&1].
__global__ __launch_bounds__(320, 1) void lstm_fused_kernel(
    const float* __restrict__ x,
    const float* __restrict__ w_ih1, const float* __restrict__ w_hh1,
    const float* __restrict__ b_ih1, const float* __restrict__ b_hh1,
    const float* __restrict__ w_ih2, const float* __restrict__ w_hh2,
    const float* __restrict__ b_ih2, const float* __restrict__ b_hh2,
    const float* __restrict__ fc_w, const float* __restrict__ fc_b,
    float* __restrict__ out)
{
  const int tid  = threadIdx.x;
  const int lane = tid & 63;
  const int wave = tid >> 6;      // 0..3 lstm2, 4 lstm1
  const int l15  = lane & 15;
  const int quad = lane >> 4;
  const int b0   = blockIdx.x * 16;

  // a2[buf][batch16][col72]: h2 0-49 | h1 50-54 | zero 55-71
  __shared__ __align__(16) unsigned short a2h[2][16*72], a2l[2][16*72];
  // x ring: [slot8][batch16][col24] (dims 0-15, pad)
  __shared__ __align__(16) unsigned short xrh[8][16*24], xrl[8][16*24];
  // lstm1 h state: [batch16][col24]: h1 0-4 | zero 5-15 (cols 16-23 pad)
  __shared__ __align__(16) unsigned short a1h[16*24], a1l[16*24];
  __shared__ float h2f[16*52];
  __shared__ unsigned cnt1, cnt2;

  // ---- weights (registers, loop-invariant), split hi/lo bf16 ----
  bf16x8 Bh[4][2], Bl[4][2];
  float bias[4];
  float cst[4] = {0.f,0.f,0.f,0.f};
  const int cg = wave*16 + l15;          // lstm2 cell col (waves 0-3)

  if (wave < 4){
    bool valid = cg < H2;
#pragma unroll
    for (int tt=0; tt<4; ++tt){
      int grow = tt*H2 + cg;
#pragma unroll
      for (int kt=0; kt<2; ++kt){
#pragma unroll
        for (int j=0;j<8;j++){
          int kk = kt*32 + quad*8 + j;
          float w = 0.f;
          if (valid){
            if (kk < H2)         w = w_hh2[grow*H2 + kk];
            else if (kk < H2+H1) w = w_ih2[grow*H1 + (kk-H2)];
          }
          short hi, lo; wsplit(w, hi, lo);
          Bh[tt][kt][j] = hi; Bl[tt][kt][j] = lo;
        }
      }
      bias[tt] = valid ? (b_ih2[grow] + b_hh2[grow]) : 0.f;
    }
  } else {
    bool valid = l15 < H1;
#pragma unroll
    for (int tt=0; tt<4; ++tt){
      int grow = tt*H1 + l15;
#pragma unroll
      for (int j=0;j<8;j++){
        int kk = quad*8 + j;
        float w = 0.f;
        if (valid){
          if (kk < IN_DIM)         w = w_ih1[grow*IN_DIM + kk];
          else if (kk < IN_DIM+H1) w = w_hh1[grow*H1 + (kk-IN_DIM)];
        }
        short hi, lo; wsplit(w, hi, lo);
        Bh[tt][0][j] = hi; Bl[tt][0][j] = lo;
        Bh[tt][1][j] = 0;  Bl[tt][1][j] = 0;
      }
      bias[tt] = valid ? (b_ih1[grow] + b_hh1[grow]) : 0.f;
    }
  }

  // ---- zero LDS state ----
  { unsigned short* p = &a2h[0][0]; for (int i=tid;i<2*16*72;i+=320) p[i]=0; }
  { unsigned short* p = &a2l[0][0]; for (int i=tid;i<2*16*72;i+=320) p[i]=0; }
  { unsigned short* p = &a1h[0];    for (int i=tid;i<16*24;i+=320)   p[i]=0; }
  { unsigned short* p = &a1l[0];    for (int i=tid;i<16*24;i+=320)   p[i]=0; }
  if (tid == 0){ cnt1 = 0; cnt2 = 0; }

  // preload x(0..7) into ring (wave 4)
  const int xb = lane >> 2;        // batch
  const int xd = (lane & 3) * 4;   // dim base
  if (wave == 4){
#pragma unroll
    for (int s=0;s<8;s++){
      float4 v = *(const float4*)&x[((size_t)(b0+xb)*T_STEPS + s)*IN_DIM + xd];
      cvt_store(&xrh[s][xb*24+xd], &xrl[s][xb*24+xd], v);
    }
  }
  __syncthreads();   // one-time: init visible everywhere

  if (wave == 4){
    // ================= lstm1, fully in-wave =================
    float4 pf0, pf1, pf2, pf3;
    bool pend = false;
    for (int s=0; s<T_STEPS; ++s){
      if (s >= 2) spin_ge(&cnt2, 4u*(unsigned)(s-1));   // don't clobber a2[s&1] h1 while read

      // issue x prefetch for x(s+4..s+7) every 4th step
      if ((s & 3) == 0 && s+4 < T_STEPS){
        const float* xp = &x[((size_t)(b0+xb)*T_STEPS + (s+4))*IN_DIM + xd];
        pf0 = *(const float4*)(xp + 0*IN_DIM);
        pf1 = *(const float4*)(xp + 1*IN_DIM);
        pf2 = *(const float4*)(xp + 2*IN_DIM);
        pf3 = *(const float4*)(xp + 3*IN_DIM);
        pend = true;
      }

      // A-frag: quads 0-1 = x(slot s&7), quads 2-3 = h1 (a1)
      const int slot = s & 7;
      bf16x8 ah, al;
      if (quad < 2){
        ah = *(const bf16x8*)&xrh[slot][l15*24 + quad*8];
        al = *(const bf16x8*)&xrl[slot][l15*24 + quad*8];
      } else {
        ah = *(const bf16x8*)&a1h[l15*24 + (quad-2)*8];
        al = *(const bf16x8*)&a1l[l15*24 + (quad-2)*8];
      }
      f32x4 acc[4];
#pragma unroll
      for (int tt=0; tt<4; ++tt){
        f32x4 cA = {bias[tt],bias[tt],bias[tt],bias[tt]};
        cA = __builtin_amdgcn_mfma_f32_16x16x32_bf16(ah, Bh[tt][0], cA, 0,0,0);
        f32x4 cB = {0.f,0.f,0.f,0.f};
        cB = __builtin_amdgcn_mfma_f32_16x16x32_bf16(ah, Bl[tt][0], cB, 0,0,0);
        cB = __builtin_amdgcn_mfma_f32_16x16x32_bf16(al, Bh[tt][0], cB, 0,0,0);
        acc[tt] = cA + cB;
      }
#pragma unroll
      for (int r=0;r<4;r++){
        float gi = sigm(acc[0][r]);
        float gf = sigm(acc[1][r]);
        float gg = tanh_(acc[2][r]);
        float go = sigm(acc[3][r]);
        cst[r] = gf*cst[r] + gi*gg;
        float h = go * tanh_(cst[r]);
        if (l15 < H1){
          unsigned short hh, hl; split1(h, hh, hl);
          int row = quad*4 + r;
          a1h[row*24 + l15] = hh;
          a1l[row*24 + l15] = hl;
          a2h[s&1][row*72 + H2 + l15] = hh;
          a2l[s&1][row*72 + H2 + l15] = hl;
        }
      }
      // write prefetched x into ring 2 steps after issue (slots (s+2..s+5)&7)
      if ((s & 3) == 2 && pend){
        cvt_store(&xrh[(s+2)&7][xb*24+xd], &xrl[(s+2)&7][xb*24+xd], pf0);
        cvt_store(&xrh[(s+3)&7][xb*24+xd], &xrl[(s+3)&7][xb*24+xd], pf1);
        cvt_store(&xrh[(s+4)&7][xb*24+xd], &xrl[(s+4)&7][xb*24+xd], pf2);
        cvt_store(&xrh[(s+5)&7][xb*24+xd], &xrl[(s+5)&7][xb*24+xd], pf3);
        pend = false;
      }
      __threadfence_block();
      if (lane == 0) atomicAdd(&cnt1, 1u);
    }
  } else {
    // ================= lstm2, 4 waves, counter-synced =================
    const bool act = cg < H2;
    for (int t=0; t<T_STEPS; ++t){
      spin_ge(&cnt1, (unsigned)(t+1));            // h1(t) present in a2[t&1]
      if (t >= 1) spin_ge(&cnt2, 4u*(unsigned)t); // h2(t-1) present; wr buf free
      const int rd = t & 1, wr = rd ^ 1;

      const int rb = l15*72;
      bf16x8 ah0 = *(const bf16x8*)&a2h[rd][rb +      quad*8];
      bf16x8 al0 = *(const bf16x8*)&a2l[rd][rb +      quad*8];
      bf16x8 ah1 = *(const bf16x8*)&a2h[rd][rb + 32 + quad*8];
      bf16x8 al1 = *(const bf16x8*)&a2l[rd][rb + 32 + quad*8];

      f32x4 acc[4];
#pragma unroll
      for (int tt=0; tt<4; ++tt){
        f32x4 cA = {bias[tt],bias[tt],bias[tt],bias[tt]};
        cA = __builtin_amdgcn_mfma_f32_16x16x32_bf16(ah0, Bh[tt][0], cA, 0,0,0);
        cA = __builtin_amdgcn_mfma_f32_16x16x32_bf16(al0, Bh[tt][0], cA, 0,0,0);
        cA = __builtin_amdgcn_mfma_f32_16x16x32_bf16(ah0, Bl[tt][0], cA, 0,0,0);
        f32x4 cB = {0.f,0.f,0.f,0.f};
        cB = __builtin_amdgcn_mfma_f32_16x16x32_bf16(ah1, Bh[tt][1], cB, 0,0,0);
        cB = __builtin_amdgcn_mfma_f32_16x16x32_bf16(al1, Bh[tt][1], cB, 0,0,0);
        cB = __builtin_amdgcn_mfma_f32_16x16x32_bf16(ah1, Bl[tt][1], cB, 0,0,0);
        acc[tt] = cA + cB;
      }
#pragma unroll
      for (int r=0;r<4;r++){
        float gi = sigm(acc[0][r]);
        float gf = sigm(acc[1][r]);
        float gg = tanh_(acc[2][r]);
        float go = sigm(acc[3][r]);
        cst[r] = gf*cst[r] + gi*gg;
        float h = go * tanh_(cst[r]);
        if (act){
          unsigned short hh, hl; split1(h, hh, hl);
          int row = quad*4 + r;
          a2h[wr][row*72 + cg] = hh;
          a2l[wr][row*72 + cg] = hl;
          if (t == T_STEPS-1){
            out[(size_t)B_TOTAL*NCLS + (size_t)(b0+row)*H2 + cg] = h;
            h2f[row*52 + cg] = h;
          }
        }
      }
      __threadfence_block();
      if (lane == 0) atomicAdd(&cnt2, 1u);
    }
  }

  __syncthreads();
  // fused FC: 16 batches x 20 outputs = 320 threads exactly
  {
    int b = tid / 20, o = tid % 20;
    float s = fc_b[o];
#pragma unroll 10
    for (int k=0;k<H2;k++) s += fc_w[o*H2+k] * h2f[b*52+k];
    out[(size_t)(b0+b)*NCLS + o] = s;
  }
}

extern "C" void kernel_launch(void* const* d_in, const int* in_sizes, int n_in,
                              void* d_out, int out_size, void* d_ws, size_t ws_size,
                              hipStream_t stream) {
  const float* x     = (const float*)d_in[0];
  const float* w_ih1 = (const float*)d_in[1];
  const float* w_hh1 = (const float*)d_in[2];
  const float* b_ih1 = (const float*)d_in[3];
  const float* b_hh1 = (const float*)d_in[4];
  const float* w_ih2 = (const float*)d_in[5];
  const float* w_hh2 = (const float*)d_in[6];
  const float* b_ih2 = (const float*)d_in[7];
  const float* b_hh2 = (const float*)d_in[8];
  const float* fc_w  = (const float*)d_in[9];
  const float* fc_b  = (const float*)d_in[10];
  float* out = (float*)d_out;

  lstm_fused_kernel<<<dim3(B_TOTAL/16), dim3(320), 0, stream>>>(
      x, w_ih1, w_hh1, b_ih1, b_hh1, w_ih2, w_hh2, b_ih2, b_hh2, fc_w, fc_b, out);
}

// Round 5
// 723.000 us; speedup vs baseline: 1.0486x; 1.0486x over previous
//
#include <hip/hip_runtime.h>
#include <stdint.h>

#define B_TOTAL 4096
#define T_STEPS 512
#define IN_DIM 16
#define H1 5
#define H2 50
#define NCLS 20

typedef __attribute__((ext_vector_type(8))) short bf16x8;
typedef __attribute__((ext_vector_type(4))) float f32x4;

#define LOG2E 1.44269504f
__device__ inline float sigm(float x){
  float e = __builtin_amdgcn_exp2f(-LOG2E * x);
  return __builtin_amdgcn_rcpf(1.0f + e);
}
__device__ inline float tanh_(float x){
  float e = __builtin_amdgcn_exp2f((2.0f*LOG2E) * x);
  float r = __builtin_amdgcn_rcpf(1.0f + e);
  return fmaf(-2.0f, r, 1.0f);
}
// dword = [top16(a) | top16(b)]  (memory shorts: [0]=b, [1]=a)
__device__ inline unsigned pack_top(float a, float b){
  return __builtin_amdgcn_perm(__float_as_uint(a), __float_as_uint(b), 0x07060302u);
}
__device__ inline void cvt_store(unsigned short* dh, unsigned short* dl, float4 v){
  uint2 H, L;
  H.x = pack_top(v.y, v.x);
  H.y = pack_top(v.w, v.z);
  float r0 = v.x - __uint_as_float(__float_as_uint(v.x) & 0xFFFF0000u);
  float r1 = v.y - __uint_as_float(__float_as_uint(v.y) & 0xFFFF0000u);
  float r2 = v.z - __uint_as_float(__float_as_uint(v.z) & 0xFFFF0000u);
  float r3 = v.w - __uint_as_float(__float_as_uint(v.w) & 0xFFFF0000u);
  L.x = pack_top(r1, r0);
  L.y = pack_top(r3, r2);
  *(uint2*)dh = H; *(uint2*)dl = L;
}
__device__ inline void split1(float h, unsigned short& hi, unsigned short& lo){
  unsigned u = __float_as_uint(h);
  hi = (unsigned short)(u >> 16);
  float r = h - __uint_as_float(u & 0xFFFF0000u);
  lo = (unsigned short)(__float_as_uint(r) >> 16);
}
__device__ inline void wsplit(float w, short& hi, short& lo){
  unsigned u = __float_as_uint(w);
  hi = (short)(u >> 16);
  float r = w - __uint_as_float(u & 0xFFFF0000u);
  lo = (short)(__float_as_uint(r) >> 16);
}

// raw barrier: no vmcnt drain (x prefetch stays in flight), LDS made visible
// by explicit lgkmcnt(0) before the barrier.
#define LDS_FENCE() __asm__ volatile("s_waitcnt lgkmcnt(0)" ::: "memory")
#define BARRIER()   __asm__ volatile("s_barrier" ::: "memory")

// Fused 2-layer LSTM + FC. grid 256 (16-batch tiles), block 320 (5 waves).
// ONE raw s_barrier per superstep. Waves 0-3: lstm2 (16 cell-cols each, all 4
// gate types in registers). Wave 4: lstm1, one step AHEAD (computes h1(t+1)
// during superstep t); its a1/x-ring state is wave-private (in-order LDS).
// a2 double-buffered: superstep t reads a2[t&1] (h2(t-1), h1(t)), writes
// a2[(t+1)&1] (h2(t), h1(t+1)). MFMA dep chains are depth-2 (3 parallel
// 2-chains + 2 vector adds per gate).
__global__ __launch_bounds__(320, 1) void lstm_fused_kernel(
    const float* __restrict__ x,
    const float* __restrict__ w_ih1, const float* __restrict__ w_hh1,
    const float* __restrict__ b_ih1, const float* __restrict__ b_hh1,
    const float* __restrict__ w_ih2, const float* __restrict__ w_hh2,
    const float* __restrict__ b_ih2, const float* __restrict__ b_hh2,
    const float* __restrict__ fc_w, const float* __restrict__ fc_b,
    float* __restrict__ out)
{
  const int tid  = threadIdx.x;
  const int lane = tid & 63;
  const int wave = tid >> 6;      // 0..3 lstm2, 4 lstm1
  const int l15  = lane & 15;
  const int quad = lane >> 4;
  const int b0   = blockIdx.x * 16;

  // a2[buf][batch16][col72]: h2 0-49 | h1 50-54 | zero 55-71
  __shared__ __align__(16) unsigned short a2h[2][16*72], a2l[2][16*72];
  // x ring: [slot8][batch16][col24] (dims 0-15; cols 16-23 never read)
  __shared__ __align__(16) unsigned short xrh[8][16*24], xrl[8][16*24];
  // lstm1 h state: [batch16][col24]: h1 0-4 | zero 5-15 (cols 16-23 unread)
  __shared__ __align__(16) unsigned short a1h[16*24], a1l[16*24];
  __shared__ float h2f[16*52];

  // ---- weights (registers, loop-invariant), split hi/lo bf16 ----
  bf16x8 Bh[4][2], Bl[4][2];
  float bias[4];
  float cst[4] = {0.f,0.f,0.f,0.f};
  const int cg = wave*16 + l15;          // lstm2 cell col (waves 0-3)

  if (wave < 4){
    bool valid = cg < H2;
#pragma unroll
    for (int tt=0; tt<4; ++tt){
      int grow = tt*H2 + cg;
#pragma unroll
      for (int kt=0; kt<2; ++kt){
#pragma unroll
        for (int j=0;j<8;j++){
          int kk = kt*32 + quad*8 + j;
          float w = 0.f;
          if (valid){
            if (kk < H2)         w = w_hh2[grow*H2 + kk];
            else if (kk < H2+H1) w = w_ih2[grow*H1 + (kk-H2)];
          }
          short hi, lo; wsplit(w, hi, lo);
          Bh[tt][kt][j] = hi; Bl[tt][kt][j] = lo;
        }
      }
      bias[tt] = valid ? (b_ih2[grow] + b_hh2[grow]) : 0.f;
    }
  } else {
    bool valid = l15 < H1;
#pragma unroll
    for (int tt=0; tt<4; ++tt){
      int grow = tt*H1 + l15;
#pragma unroll
      for (int j=0;j<8;j++){
        int kk = quad*8 + j;
        float w = 0.f;
        if (valid){
          if (kk < IN_DIM)         w = w_ih1[grow*IN_DIM + kk];
          else if (kk < IN_DIM+H1) w = w_hh1[grow*H1 + (kk-IN_DIM)];
        }
        short hi, lo; wsplit(w, hi, lo);
        Bh[tt][0][j] = hi; Bl[tt][0][j] = lo;
        Bh[tt][1][j] = 0;  Bl[tt][1][j] = 0;
      }
      bias[tt] = valid ? (b_ih1[grow] + b_hh1[grow]) : 0.f;
    }
  }

  // ---- zero LDS state ----
  { unsigned short* p = &a2h[0][0]; for (int i=tid;i<2*16*72;i+=320) p[i]=0; }
  { unsigned short* p = &a2l[0][0]; for (int i=tid;i<2*16*72;i+=320) p[i]=0; }
  { unsigned short* p = &a1h[0];    for (int i=tid;i<16*24;i+=320)   p[i]=0; }
  { unsigned short* p = &a1l[0];    for (int i=tid;i<16*24;i+=320)   p[i]=0; }

  // preload x(0..7) into ring (wave 4, private)
  const int xb = lane >> 2;        // batch
  const int xd = (lane & 3) * 4;   // dim base
  if (wave == 4){
#pragma unroll
    for (int s=0;s<8;s++){
      float4 v = *(const float4*)&x[((size_t)(b0+xb)*T_STEPS + s)*IN_DIM + xd];
      cvt_store(&xrh[s][xb*24+xd], &xrl[s][xb*24+xd], v);
    }
  }
  __syncthreads();   // one-time: zeros + ring visible

  float4 pf0, pf1, pf2, pf3;
  bool pend = false;

  // superstep t: lstm2 computes h2(t) (t>=0); lstm1 computes h1(t+1).
  for (int t=-1; t<T_STEPS; ++t){
    const int rd = t & 1;        // (-1)&1 == 1
    const int wr = rd ^ 1;

    if (wave == 4){
      const int s = t + 1;       // lstm1 step
      if (s < T_STEPS){
        // x prefetch: at s%4==0 load x(s+4..s+7); at s%4==2 store to ring
        if ((s & 3) == 0 && s+4 < T_STEPS){
          const float* xp = &x[((size_t)(b0+xb)*T_STEPS + (s+4))*IN_DIM + xd];
          pf0 = *(const float4*)(xp + 0*IN_DIM);
          pf1 = *(const float4*)(xp + 1*IN_DIM);
          pf2 = *(const float4*)(xp + 2*IN_DIM);
          pf3 = *(const float4*)(xp + 3*IN_DIM);
          pend = true;
        }
        const int slot = s & 7;
        bf16x8 ah, al;
        if (quad < 2){
          ah = *(const bf16x8*)&xrh[slot][l15*24 + quad*8];
          al = *(const bf16x8*)&xrl[slot][l15*24 + quad*8];
        } else {
          ah = *(const bf16x8*)&a1h[l15*24 + (quad-2)*8];
          al = *(const bf16x8*)&a1l[l15*24 + (quad-2)*8];
        }
        f32x4 acc[4];
#pragma unroll
        for (int tt=0; tt<4; ++tt){
          f32x4 cA = {bias[tt],bias[tt],bias[tt],bias[tt]};
          cA = __builtin_amdgcn_mfma_f32_16x16x32_bf16(ah, Bh[tt][0], cA, 0,0,0);
          f32x4 cB = {0.f,0.f,0.f,0.f};
          cB = __builtin_amdgcn_mfma_f32_16x16x32_bf16(al, Bh[tt][0], cB, 0,0,0);
          cB = __builtin_amdgcn_mfma_f32_16x16x32_bf16(ah, Bl[tt][0], cB, 0,0,0);
          acc[tt] = cA + cB;
        }
#pragma unroll
        for (int r=0;r<4;r++){
          float gi = sigm(acc[0][r]);
          float gf = sigm(acc[1][r]);
          float gg = tanh_(acc[2][r]);
          float go = sigm(acc[3][r]);
          cst[r] = gf*cst[r] + gi*gg;
          float h = go * tanh_(cst[r]);
          if (l15 < H1){
            unsigned short hh, hl; split1(h, hh, hl);
            int row = quad*4 + r;
            a1h[row*24 + l15] = hh;
            a1l[row*24 + l15] = hl;
            a2h[wr][row*72 + H2 + l15] = hh;
            a2l[wr][row*72 + H2 + l15] = hl;
          }
        }
        if ((s & 3) == 2 && pend){
          cvt_store(&xrh[(s+2)&7][xb*24+xd], &xrl[(s+2)&7][xb*24+xd], pf0);
          cvt_store(&xrh[(s+3)&7][xb*24+xd], &xrl[(s+3)&7][xb*24+xd], pf1);
          cvt_store(&xrh[(s+4)&7][xb*24+xd], &xrl[(s+4)&7][xb*24+xd], pf2);
          cvt_store(&xrh[(s+5)&7][xb*24+xd], &xrl[(s+5)&7][xb*24+xd], pf3);
          pend = false;
        }
      }
    } else if (t >= 0){
      const int rb = l15*72;
      bf16x8 ah0 = *(const bf16x8*)&a2h[rd][rb +      quad*8];
      bf16x8 al0 = *(const bf16x8*)&a2l[rd][rb +      quad*8];
      bf16x8 ah1 = *(const bf16x8*)&a2h[rd][rb + 32 + quad*8];
      bf16x8 al1 = *(const bf16x8*)&a2l[rd][rb + 32 + quad*8];

      f32x4 acc[4];
#pragma unroll
      for (int tt=0; tt<4; ++tt){
        // three parallel depth-2 chains + 2 adds
        f32x4 c0 = {bias[tt],bias[tt],bias[tt],bias[tt]};
        c0 = __builtin_amdgcn_mfma_f32_16x16x32_bf16(ah0, Bh[tt][0], c0, 0,0,0);
        c0 = __builtin_amdgcn_mfma_f32_16x16x32_bf16(al0, Bh[tt][0], c0, 0,0,0);
        f32x4 c1 = {0.f,0.f,0.f,0.f};
        c1 = __builtin_amdgcn_mfma_f32_16x16x32_bf16(ah0, Bl[tt][0], c1, 0,0,0);
        c1 = __builtin_amdgcn_mfma_f32_16x16x32_bf16(ah1, Bh[tt][1], c1, 0,0,0);
        f32x4 c2 = {0.f,0.f,0.f,0.f};
        c2 = __builtin_amdgcn_mfma_f32_16x16x32_bf16(al1, Bh[tt][1], c2, 0,0,0);
        c2 = __builtin_amdgcn_mfma_f32_16x16x32_bf16(ah1, Bl[tt][1], c2, 0,0,0);
        acc[tt] = (c0 + c1) + c2;
      }
      const bool act = cg < H2;
#pragma unroll
      for (int r=0;r<4;r++){
        float gi = sigm(acc[0][r]);
        float gf = sigm(acc[1][r]);
        float gg = tanh_(acc[2][r]);
        float go = sigm(acc[3][r]);
        cst[r] = gf*cst[r] + gi*gg;
        float h = go * tanh_(cst[r]);
        if (act){
          unsigned short hh, hl; split1(h, hh, hl);
          int row = quad*4 + r;
          a2h[wr][row*72 + cg] = hh;
          a2l[wr][row*72 + cg] = hl;
          if (t == T_STEPS-1){
            out[(size_t)B_TOTAL*NCLS + (size_t)(b0+row)*H2 + cg] = h;
            h2f[row*52 + cg] = h;
          }
        }
      }
    }

    LDS_FENCE();   // own LDS writes committed
    BARRIER();     // publish h2(t), h1(t+1); no vmcnt drain
  }

  __syncthreads();
  // fused FC: 16 batches x 20 outputs = 320 threads exactly
  {
    int b = tid / 20, o = tid % 20;
    float s = fc_b[o];
#pragma unroll 10
    for (int k=0;k<H2;k++) s += fc_w[o*H2+k] * h2f[b*52+k];
    out[(size_t)(b0+b)*NCLS + o] = s;
  }
}

extern "C" void kernel_launch(void* const* d_in, const int* in_sizes, int n_in,
                              void* d_out, int out_size, void* d_ws, size_t ws_size,
                              hipStream_t stream) {
  const float* x     = (const float*)d_in[0];
  const float* w_ih1 = (const float*)d_in[1];
  const float* w_hh1 = (const float*)d_in[2];
  const float* b_ih1 = (const float*)d_in[3];
  const float* b_hh1 = (const float*)d_in[4];
  const float* w_ih2 = (const float*)d_in[5];
  const float* w_hh2 = (const float*)d_in[6];
  const float* b_ih2 = (const float*)d_in[7];
  const float* b_hh2 = (const float*)d_in[8];
  const float* fc_w  = (const float*)d_in[9];
  const float* fc_b  = (const float*)d_in[10];
  float* out = (float*)d_out;

  lstm_fused_kernel<<<dim3(B_TOTAL/16), dim3(320), 0, stream>>>(
      x, w_ih1, w_hh1, b_ih1, b_hh1, w_ih2, w_hh2, b_ih2, b_hh2, fc_w, fc_b, out);
}